// Round 2
// baseline (7528.144 us; speedup 1.0000x reference)
//
#include <hip/hip_runtime.h>
#include <hip/hip_bf16.h>

// ---------------- problem constants ----------------
#define Bz   32
#define Nn_  577
#define Cc   768
#define Hh   3072
#define Mrows (Bz * Nn_)          // 18464
#define OUT_X (Mrows * Cc)        // 14,180,352 floats
#define SCALE 0.03608439182435161f // 768^-0.5

// ---------------- block reduction helpers (256-thread 1-D blocks) ----------------
__device__ __forceinline__ float bsum(float v, float* sm) {
    #pragma unroll
    for (int o = 32; o > 0; o >>= 1) v += __shfl_down(v, o, 64);
    int lane = threadIdx.x & 63, wid = threadIdx.x >> 6;
    if (lane == 0) sm[wid] = v;
    __syncthreads();
    float r = sm[0] + sm[1] + sm[2] + sm[3];
    __syncthreads();
    return r;
}
__device__ __forceinline__ float bmax(float v, float* sm) {
    #pragma unroll
    for (int o = 32; o > 0; o >>= 1) v = fmaxf(v, __shfl_down(v, o, 64));
    int lane = threadIdx.x & 63, wid = threadIdx.x >> 6;
    if (lane == 0) sm[wid] = v;
    __syncthreads();
    float r = fmaxf(fmaxf(sm[0], sm[1]), fmaxf(sm[2], sm[3]));
    __syncthreads();
    return r;
}

// ---------------- LayerNorm: one block per row of 768 ----------------
__global__ void ln_kernel(const float* __restrict__ x, const float* __restrict__ w,
                          const float* __restrict__ b, float* __restrict__ out) {
    __shared__ float sm[8];
    long long row = blockIdx.x;
    const float* xr = x + row * Cc;
    float v[3]; float s = 0.f;
    #pragma unroll
    for (int i = 0; i < 3; ++i) { v[i] = xr[threadIdx.x + i * 256]; s += v[i]; }
    float mu = bsum(s, sm) * (1.f / (float)Cc);
    float sq = 0.f;
    #pragma unroll
    for (int i = 0; i < 3; ++i) { float d = v[i] - mu; sq += d * d; }
    float var = bsum(sq, sm + 4) * (1.f / (float)Cc);
    float inv = rsqrtf(var + 1e-5f);
    float* orow = out + row * Cc;
    #pragma unroll
    for (int i = 0; i < 3; ++i) {
        int c = threadIdx.x + i * 256;
        orow[c] = (v[i] - mu) * inv * w[c] + b[c];
    }
}

// ---------------- softmax over rows of length 577 (in place) ----------------
__global__ void softmax_kernel(float* __restrict__ S) {
    __shared__ float sm[8];
    long long row = blockIdx.x;
    float* r = S + row * Nn_;
    float v[3]; float mx = -1e30f;
    #pragma unroll
    for (int i = 0; i < 3; ++i) {
        int c = threadIdx.x + i * 256;
        v[i] = (c < Nn_) ? r[c] : -1e30f;
        mx = fmaxf(mx, v[i]);
    }
    mx = bmax(mx, sm);
    float s = 0.f;
    #pragma unroll
    for (int i = 0; i < 3; ++i) {
        int c = threadIdx.x + i * 256;
        v[i] = (c < Nn_) ? expf(v[i] - mx) : 0.f;
        s += v[i];
    }
    s = bsum(s, sm + 4);
    float inv = 1.f / s;
    #pragma unroll
    for (int i = 0; i < 3; ++i) {
        int c = threadIdx.x + i * 256;
        if (c < Nn_) r[c] = v[i] * inv;
    }
}

// ---------------- token_attn extraction (per batch-group) ----------------
__global__ void token_attn_kernel(const float* __restrict__ S, float* __restrict__ out, int G) {
    int idx = blockIdx.x * 256 + threadIdx.x;
    if (idx >= G * 576) return;
    int b = idx / 576, t = idx % 576;
    out[idx] = S[(long long)b * Nn_ * Nn_ + (1 + t)];
}

// ---------------- generic tiled GEMM ----------------
// out[m,n] = alpha * sum_k A[m,k] * B'[n,k] (+ bias[n]) with epilogues.
// TRANS_B: B is (N,K) row-major (NT). else B is (K,N) row-major (NN).
// EPI: 0 none | 1 (v+bias)*2 | 2 exact gelu | 3 accumulate (O += v)
// WT : write transposed -> O[n*ldo + m]
#define BM 64
#define BN 64
#define BK 16
template<bool TRANS_B, int EPI, bool WT>
__global__ void gemm_kernel(const float* __restrict__ A, long long sAb, int lda,
                            const float* __restrict__ B, long long sBb, int ldb,
                            const float* __restrict__ bias,
                            float* __restrict__ O, long long sOb, int ldo,
                            int M, int Nc, int K, float alpha)
{
    __shared__ float As[BK][BM + 1];
    __shared__ float Bs[BK][BN + 1];
    int bz = blockIdx.z;
    A += (long long)bz * sAb; B += (long long)bz * sBb; O += (long long)bz * sOb;
    int n0 = blockIdx.x * BN;
    int m0 = blockIdx.y * BM;
    int tid = threadIdx.y * 16 + threadIdx.x;
    float acc[4][4] = {};
    for (int k0 = 0; k0 < K; k0 += BK) {
        #pragma unroll
        for (int it = 0; it < 4; ++it) {
            int e = tid + it * 256;
            int r = e >> 4, c = e & 15;
            int m = m0 + r, k = k0 + c;
            As[c][r] = (m < M && k < K) ? A[(long long)m * lda + k] : 0.f;
        }
        if (TRANS_B) {
            #pragma unroll
            for (int it = 0; it < 4; ++it) {
                int e = tid + it * 256;
                int r = e >> 4, c = e & 15;
                int n = n0 + r, k = k0 + c;
                Bs[c][r] = (n < Nc && k < K) ? B[(long long)n * ldb + k] : 0.f;
            }
        } else {
            #pragma unroll
            for (int it = 0; it < 4; ++it) {
                int e = tid + it * 256;
                int r = e >> 6, c = e & 63;
                int k = k0 + r, n = n0 + c;
                Bs[r][c] = (k < K && n < Nc) ? B[(long long)k * ldb + n] : 0.f;
            }
        }
        __syncthreads();
        #pragma unroll
        for (int kk = 0; kk < BK; ++kk) {
            float a[4], w[4];
            #pragma unroll
            for (int i = 0; i < 4; ++i) a[i] = As[kk][threadIdx.y * 4 + i];
            #pragma unroll
            for (int j = 0; j < 4; ++j) w[j] = Bs[kk][threadIdx.x * 4 + j];
            #pragma unroll
            for (int i = 0; i < 4; ++i)
                #pragma unroll
                for (int j = 0; j < 4; ++j)
                    acc[i][j] = fmaf(a[i], w[j], acc[i][j]);
        }
        __syncthreads();
    }
    #pragma unroll
    for (int i = 0; i < 4; ++i) {
        int m = m0 + threadIdx.y * 4 + i;
        if (m >= M) continue;
        #pragma unroll
        for (int j = 0; j < 4; ++j) {
            int n = n0 + threadIdx.x * 4 + j;
            if (n >= Nc) continue;
            float v = acc[i][j] * alpha;
            if (bias) v += bias[n];
            if (EPI == 1) v *= 2.f;
            else if (EPI == 2) v = 0.5f * v * (1.f + erff(v * 0.70710678118654752f));
            long long oi = WT ? ((long long)n * ldo + m) : ((long long)m * ldo + n);
            if (EPI == 3) O[oi] += v;
            else O[oi] = v;
        }
    }
}

static inline long long bytesA(int G) {
    // h/y_t (G*577*768) + qkv (G*577*2304) + S (G*577*577), fp32
    return 4LL * ((long long)G * Nn_ * Cc + (long long)G * Nn_ * 3 * Cc + (long long)G * Nn_ * Nn_);
}

// ---------------- launcher ----------------
extern "C" void kernel_launch(void* const* d_in, const int* in_sizes, int n_in,
                              void* d_out, int out_size, void* d_ws, size_t ws_size,
                              hipStream_t stream) {
    const float* x      = (const float*)d_in[0];
    const float* n1w    = (const float*)d_in[1];
    const float* n1b    = (const float*)d_in[2];
    const float* qkv_w  = (const float*)d_in[3];
    const float* proj_w = (const float*)d_in[4];
    const float* proj_b = (const float*)d_in[5];
    const float* n2w    = (const float*)d_in[6];
    const float* n2b    = (const float*)d_in[7];
    const float* fc1w   = (const float*)d_in[8];
    const float* fc1b   = (const float*)d_in[9];
    const float* fc2w   = (const float*)d_in[10];
    const float* fc2b   = (const float*)d_in[11];
    float* out = (float*)d_out;
    float* x2  = out;               // x2 = 2*a lives in d_out; fc2 accumulates into it
    float* tok = out + OUT_X;

    // ---- choose batch-group size G and MLP row-chunk CH from ws_size ----
    int G = 1;
    {
        const int opts[5] = {16, 8, 4, 2, 1};
        for (int i = 0; i < 5; ++i)
            if (bytesA(opts[i]) <= (long long)ws_size) { G = opts[i]; break; }
    }
    int CH = Nn_;
    {
        const int opts[5] = {16 * Nn_, 8 * Nn_, 4 * Nn_, 2 * Nn_, Nn_};
        for (int i = 0; i < 5; ++i)
            if (4LL * opts[i] * (Cc + Hh) <= (long long)ws_size) { CH = opts[i]; break; }
    }

    char* ws = (char*)d_ws;
    // phase A layout (per batch-group): h/y_t | qkv | S
    float* hy  = (float*)(ws);
    float* qkv = hy  + (long long)G * Nn_ * Cc;
    float* S   = qkv + (long long)G * Nn_ * 3 * Cc;
    // phase B layout (reuses same region): g | t
    float* g = (float*)(ws);
    float* t = g + (long long)CH * Cc;

    dim3 thr(16, 16);

    // ================= phase A: attention, per group of G batches =================
    for (int b0 = 0; b0 < Bz; b0 += G) {
        int MR = G * Nn_;                         // rows in this group
        const float* xg = x + (long long)b0 * Nn_ * Cc;

        // LN1: x -> hy
        ln_kernel<<<MR, 256, 0, stream>>>(xg, n1w, n1b, hy);

        // qkv = hy @ qkv_w^T   (MR x 2304 x 768)
        gemm_kernel<true, 0, false><<<dim3(36, (MR + BM - 1) / BM, 1), thr, 0, stream>>>(
            hy, 0, Cc, qkv_w, 0, Cc, nullptr, qkv, 0, 3 * Cc, MR, 3 * Cc, Cc, 1.f);

        // S = scale * q @ k^T per batch (577 x 577 x 768)
        gemm_kernel<true, 0, false><<<dim3(10, 10, G), thr, 0, stream>>>(
            qkv, (long long)Nn_ * 3 * Cc, 3 * Cc,
            qkv + Cc, (long long)Nn_ * 3 * Cc, 3 * Cc,
            nullptr, S, (long long)Nn_ * Nn_, Nn_, Nn_, Nn_, Cc, SCALE);

        // softmax rows of S
        softmax_kernel<<<MR, 256, 0, stream>>>(S);

        // token_attn = S[:,0,1:]
        token_attn_kernel<<<(G * 576 + 255) / 256, 256, 0, stream>>>(
            S, tok + (long long)b0 * 576, G);

        // y_t[c][n] = sum_m S[n,m] v[m,c]  (NN gemm, transposed write) per batch
        // overwrites hy (h is dead after qkv)
        gemm_kernel<false, 0, true><<<dim3(12, 10, G), thr, 0, stream>>>(
            S, (long long)Nn_ * Nn_, Nn_,
            qkv + 2 * Cc, (long long)Nn_ * 3 * Cc, 3 * Cc,
            nullptr, hy, (long long)Nn_ * Cc, Nn_, Nn_, Cc, Nn_, 1.f);

        // x2 = 2*(y @ proj_w^T + proj_b)  -> d_out rows of this group
        // (hy viewed as (MR,768) row-major == transpose-reshape a-input)
        gemm_kernel<true, 1, false><<<dim3(12, (MR + BM - 1) / BM, 1), thr, 0, stream>>>(
            (const float*)hy, 0, Cc, proj_w, 0, Cc, proj_b,
            x2 + (long long)b0 * Nn_ * Cc, 0, Cc, MR, Cc, Cc, 1.f);
    }

    // ================= phase B: MLP, per row-chunk of CH rows =================
    for (int c0 = 0; c0 < Mrows; c0 += CH) {
        // LN2: x2 chunk -> g
        ln_kernel<<<CH, 256, 0, stream>>>(x2 + (long long)c0 * Cc, n2w, n2b, g);

        // t = gelu(g @ fc1_w^T + fc1_b)   (CH x 3072 x 768)
        gemm_kernel<true, 2, false><<<dim3(48, (CH + BM - 1) / BM, 1), thr, 0, stream>>>(
            g, 0, Cc, fc1w, 0, Cc, fc1b, t, 0, Hh, CH, Hh, Cc, 1.f);

        // x2 += t @ fc2_w^T + fc2_b       (CH x 768 x 3072)
        gemm_kernel<true, 3, false><<<dim3(12, (CH + BM - 1) / BM, 1), thr, 0, stream>>>(
            t, 0, Hh, fc2w, 0, Hh, fc2b, x2 + (long long)c0 * Cc, 0, Cc, CH, Cc, Hh, 1.f);
    }
}

// Round 3
// 1009.880 us; speedup vs baseline: 7.4545x; 7.4545x over previous
//
#include <hip/hip_runtime.h>
#include <hip/hip_bf16.h>

// ---------------- problem constants ----------------
#define Bz   32
#define Nn_  577
#define Np   640                    // 577 padded to 5*128
#define Cc   768
#define Hh   3072
#define Mrows (Bz * Nn_)            // 18464
#define OUT_X (Mrows * Cc)          // 14,180,352 floats
#define SCALE 0.03608439182435161f  // 768^-0.5

typedef unsigned short ushort_t;
typedef short short8 __attribute__((ext_vector_type(8)));
typedef float f32x4 __attribute__((ext_vector_type(4)));

__device__ __forceinline__ ushort_t f2b(float f) {
    __hip_bfloat16 h = __float2bfloat16(f);
    return *reinterpret_cast<ushort_t*>(&h);
}

// ---------------- async global->LDS (16B per lane) ----------------
__device__ __forceinline__ void gl16(const ushort_t* g, ushort_t* l) {
    __builtin_amdgcn_global_load_lds(
        (const __attribute__((address_space(1))) void*)g,
        (__attribute__((address_space(3))) void*)l, 16, 0, 0);
}

// ---------------- block reduction helpers (256-thread blocks) ----------------
__device__ __forceinline__ float bsum(float v, float* sm) {
    #pragma unroll
    for (int o = 32; o > 0; o >>= 1) v += __shfl_down(v, o, 64);
    int lane = threadIdx.x & 63, wid = threadIdx.x >> 6;
    if (lane == 0) sm[wid] = v;
    __syncthreads();
    float r = sm[0] + sm[1] + sm[2] + sm[3];
    __syncthreads();
    return r;
}
__device__ __forceinline__ float bmax(float v, float* sm) {
    #pragma unroll
    for (int o = 32; o > 0; o >>= 1) v = fmaxf(v, __shfl_down(v, o, 64));
    int lane = threadIdx.x & 63, wid = threadIdx.x >> 6;
    if (lane == 0) sm[wid] = v;
    __syncthreads();
    float r = fmaxf(fmaxf(sm[0], sm[1]), fmaxf(sm[2], sm[3]));
    __syncthreads();
    return r;
}

// ---------------- fp32 -> bf16 convert ----------------
__global__ void cvt_kernel(const float* __restrict__ in, ushort_t* __restrict__ out, int n) {
    int i = blockIdx.x * 256 + threadIdx.x;
    if (i < n) out[i] = f2b(in[i]);
}

// ---------------- LayerNorm: fp32 in, bf16 out ----------------
__global__ void ln_bf16(const float* __restrict__ x, const float* __restrict__ w,
                        const float* __restrict__ b, ushort_t* __restrict__ out) {
    __shared__ float sm[8];
    long long row = blockIdx.x;
    const float* xr = x + row * Cc;
    float v[3]; float s = 0.f;
    #pragma unroll
    for (int i = 0; i < 3; ++i) { v[i] = xr[threadIdx.x + i * 256]; s += v[i]; }
    float mu = bsum(s, sm) * (1.f / (float)Cc);
    float sq = 0.f;
    #pragma unroll
    for (int i = 0; i < 3; ++i) { float d = v[i] - mu; sq += d * d; }
    float var = bsum(sq, sm + 4) * (1.f / (float)Cc);
    float inv = rsqrtf(var + 1e-5f);
    ushort_t* orow = out + row * Cc;
    #pragma unroll
    for (int i = 0; i < 3; ++i) {
        int c = threadIdx.x + i * 256;
        orow[c] = f2b((v[i] - mu) * inv * w[c] + b[c]);
    }
}

// ---------------- softmax: fp32 Sf (ld 640, 577 valid) -> bf16 Sb (zero-padded) + tok ----------------
__global__ void softmax_bf16(const float* __restrict__ Sf, ushort_t* __restrict__ Sb,
                             float* __restrict__ tok) {
    __shared__ float sm[8];
    long long row = blockIdx.x;
    int b_l = (int)(row / Nn_), r = (int)(row - (long long)b_l * Nn_);
    const float* src = Sf + row * Np;
    ushort_t* dst = Sb + row * Np;
    float v[3]; float mx = -1e30f;
    #pragma unroll
    for (int i = 0; i < 3; ++i) {
        int c = threadIdx.x + i * 256;
        v[i] = (c < Nn_) ? src[c] : -1e30f;
        mx = fmaxf(mx, v[i]);
    }
    mx = bmax(mx, sm);
    float s = 0.f;
    #pragma unroll
    for (int i = 0; i < 3; ++i) {
        int c = threadIdx.x + i * 256;
        v[i] = (c < Nn_) ? expf(v[i] - mx) : 0.f;
        s += v[i];
    }
    s = bsum(s, sm + 4);
    float inv = 1.f / s;
    #pragma unroll
    for (int i = 0; i < 3; ++i) {
        int c = threadIdx.x + i * 256;
        float p = v[i] * inv;
        if (c < Np) dst[c] = (c < Nn_) ? f2b(p) : (ushort_t)0;
        if (r == 0 && c >= 1 && c < Nn_) tok[(long long)b_l * 576 + (c - 1)] = p;
    }
}

// ---------------- bf16 MFMA GEMM: C[m,n] = alpha*sum_k A[m,k]*B[n,k] (+epilogue) ----------------
// A: M x K rows (lda), clamped at M-1. B: N x K rows (ldb), clamped at Nv-1.
// grid.x covers padded N/128, grid.y covers ceil(M/128), grid.z batches.
// EPI: 0 store | 1 (v+bias)*2 | 2 exact gelu(v+bias) | 3 O += v+bias | 4 qkv scatter
#define EPS_STORE 0
#define EPS_X2    1
#define EPS_GELU  2
#define EPS_ACC   3
#define EPS_QKV   4

template<int EPI, typename OutT>
__global__ __launch_bounds__(256)
void mm_bf16(const ushort_t* __restrict__ A, long long sAb, int lda, int M,
             const ushort_t* __restrict__ B, long long sBb, int ldb, int Nv,
             const float* __restrict__ bias,
             OutT* __restrict__ O, long long sOb, int ldo,
             int K, float alpha,
             ushort_t* __restrict__ qQ, ushort_t* __restrict__ qK, ushort_t* __restrict__ qV)
{
    __shared__ __align__(16) ushort_t As[128 * 32];
    __shared__ __align__(16) ushort_t Bs[128 * 32];
    const int z = blockIdx.z;
    A += (long long)z * sAb; B += (long long)z * sBb;
    if (O) O += (long long)z * sOb;
    const int n0 = blockIdx.x * 128;
    const int m0 = blockIdx.y * 128;
    const int tid = threadIdx.x;
    const int lane = tid & 63;
    const int wv = tid >> 6;
    const int wr = (wv >> 1) << 6;       // wave row offset in tile
    const int wc = (wv & 1) << 6;        // wave col offset in tile
    const int fr = lane & 15;
    const int koff = (lane >> 4) * 8;

    // staging element indices (flat over 128x32): e = row*32 + col
    const int e0 = tid * 8, e1 = 2048 + tid * 8;
    const int ra0 = e0 >> 5, ca0 = e0 & 31;
    const int ra1 = e1 >> 5, ca1 = e1 & 31;
    const ushort_t* Ag0 = A + (long long)min(m0 + ra0, M - 1) * lda + ca0;
    const ushort_t* Ag1 = A + (long long)min(m0 + ra1, M - 1) * lda + ca1;
    const ushort_t* Bg0 = B + (long long)min(n0 + ra0, Nv - 1) * ldb + ca0;
    const ushort_t* Bg1 = B + (long long)min(n0 + ra1, Nv - 1) * ldb + ca1;

    f32x4 acc[4][4] = {};

    for (int k0 = 0; k0 < K; k0 += 32) {
        gl16(Ag0 + k0, &As[e0]);
        gl16(Ag1 + k0, &As[e1]);
        gl16(Bg0 + k0, &Bs[e0]);
        gl16(Bg1 + k0, &Bs[e1]);
        __syncthreads();
        short8 af[4], bfr[4];
        #pragma unroll
        for (int i = 0; i < 4; ++i)
            af[i] = *(const short8*)&As[(wr + i * 16 + fr) * 32 + koff];
        #pragma unroll
        for (int j = 0; j < 4; ++j)
            bfr[j] = *(const short8*)&Bs[(wc + j * 16 + fr) * 32 + koff];
        #pragma unroll
        for (int i = 0; i < 4; ++i)
            #pragma unroll
            for (int j = 0; j < 4; ++j)
                acc[i][j] = __builtin_amdgcn_mfma_f32_16x16x32_bf16(af[i], bfr[j], acc[i][j], 0, 0, 0);
        __syncthreads();
    }

    // epilogue: C row m = m0+wr+i*16+(lane>>4)*4+r ; col n = n0+wc+j*16+(lane&15)
    #pragma unroll
    for (int i = 0; i < 4; ++i) {
        int mb = m0 + wr + i * 16 + (lane >> 4) * 4;
        #pragma unroll
        for (int j = 0; j < 4; ++j) {
            int n = n0 + wc + j * 16 + fr;
            if (n >= Nv) continue;
            f32x4 v4 = acc[i][j];
            #pragma unroll
            for (int r = 0; r < 4; ++r) {
                int m = mb + r;
                if (m >= M) continue;
                float v = v4[r] * alpha;
                if constexpr (EPI == EPS_QKV) {
                    int b_l = m / Nn_, rr = m - b_l * Nn_;
                    if (n < Cc)            qQ[(long long)m * Cc + n] = f2b(v);
                    else if (n < 2 * Cc)   qK[(long long)m * Cc + (n - Cc)] = f2b(v);
                    else                   qV[((long long)b_l * Cc + (n - 2 * Cc)) * Np + rr] = f2b(v);
                } else {
                    if (bias) v += bias[n];
                    if constexpr (EPI == EPS_X2) v *= 2.f;
                    if constexpr (EPI == EPS_GELU) v = 0.5f * v * (1.f + erff(v * 0.70710678118654752f));
                    long long oi = (long long)m * ldo + n;
                    if constexpr (EPI == EPS_ACC) {
                        O[oi] += v;
                    } else {
                        if constexpr (sizeof(OutT) == 2) O[oi] = (OutT)f2b(v);
                        else                             O[oi] = (OutT)v;
                    }
                }
            }
        }
    }
}

// ---------------- launcher ----------------
extern "C" void kernel_launch(void* const* d_in, const int* in_sizes, int n_in,
                              void* d_out, int out_size, void* d_ws, size_t ws_size,
                              hipStream_t stream) {
    const float* x      = (const float*)d_in[0];
    const float* n1w    = (const float*)d_in[1];
    const float* n1b    = (const float*)d_in[2];
    const float* qkv_w  = (const float*)d_in[3];
    const float* proj_w = (const float*)d_in[4];
    const float* proj_b = (const float*)d_in[5];
    const float* n2w    = (const float*)d_in[6];
    const float* n2b    = (const float*)d_in[7];
    const float* fc1w   = (const float*)d_in[8];
    const float* fc1b   = (const float*)d_in[9];
    const float* fc2w   = (const float*)d_in[10];
    const float* fc2b   = (const float*)d_in[11];
    float* out = (float*)d_out;
    float* x2  = out;
    float* tok = out + OUT_X;

    // ---- persistent bf16 weights at ws start ----
    char* ws = (char*)d_ws;
    const long long nWq = (long long)3 * Cc * Cc;   // 1,769,472
    const long long nWp = (long long)Cc * Cc;       //   589,824
    const long long nW1 = (long long)Hh * Cc;       // 2,359,296
    const long long nW2 = (long long)Cc * Hh;       // 2,359,296
    ushort_t* wq = (ushort_t*)ws;
    ushort_t* wp = wq + nWq;
    ushort_t* w1 = wp + nWp;
    ushort_t* w2 = w1 + nW1;
    const long long WBYTES = 2 * (nWq + nWp + nW1 + nW2); // 14,155,776
    char* dyn = ws + WBYTES;
    long long avail = (long long)ws_size - WBYTES;

    // ---- adaptive sizes ----
    const long long perG = 3LL * Nn_ * Cc * 2 + (long long)Cc * Np * 2
                         + (long long)Nn_ * Np * 4 + (long long)Nn_ * Np * 2; // 5,857,536
    int G = 1;
    { const int o[5] = {16, 8, 4, 2, 1};
      for (int i = 0; i < 5; ++i) if ((long long)o[i] * perG <= avail) { G = o[i]; break; } }
    int CH = Nn_;
    { const int o[5] = {16, 8, 4, 2, 1};
      for (int i = 0; i < 5; ++i) if ((long long)o[i] * Nn_ * (Cc + Hh) * 2 <= avail) { CH = o[i] * Nn_; break; } }

    // phase A layout: hbf/Yt | Q | Kb | Vt | Sf | Sb
    ushort_t* hbf = (ushort_t*)dyn;
    ushort_t* Q   = hbf + (long long)G * Nn_ * Cc;
    ushort_t* Kb  = Q   + (long long)G * Nn_ * Cc;
    ushort_t* Vt  = Kb  + (long long)G * Nn_ * Cc;
    float*    Sf  = (float*)(Vt + (long long)G * Cc * Np);
    ushort_t* Sb  = (ushort_t*)(Sf + (long long)G * Nn_ * Np);
    ushort_t* Yt  = hbf;
    // phase B layout: g | t
    ushort_t* g = (ushort_t*)dyn;
    ushort_t* t = g + (long long)CH * Cc;

    // ---- weight conversion (every call; ws is re-poisoned) ----
    cvt_kernel<<<(int)((nWq + 255) / 256), 256, 0, stream>>>(qkv_w, wq, (int)nWq);
    cvt_kernel<<<(int)((nWp + 255) / 256), 256, 0, stream>>>(proj_w, wp, (int)nWp);
    cvt_kernel<<<(int)((nW1 + 255) / 256), 256, 0, stream>>>(fc1w, w1, (int)nW1);
    cvt_kernel<<<(int)((nW2 + 255) / 256), 256, 0, stream>>>(fc2w, w2, (int)nW2);

    // ================= phase A: attention per group of G batches =================
    for (int b0 = 0; b0 < Bz; b0 += G) {
        const int MR = G * Nn_;
        const int myM = (MR + 127) / 128;

        ln_bf16<<<MR, 256, 0, stream>>>(x + (long long)b0 * Nn_ * Cc, n1w, n1b, hbf);

        // qkv: (MR x 2304 x 768), scatter to Q | Kb | Vt
        mm_bf16<EPS_QKV, float><<<dim3(18, myM, 1), 256, 0, stream>>>(
            hbf, 0, Cc, MR, wq, 0, Cc, 3 * Cc, nullptr,
            (float*)nullptr, 0, 0, Cc, 1.f, Q, Kb, Vt);

        // Sf = scale * Q @ K^T per batch (577x577 valid, ld 640)
        mm_bf16<EPS_STORE, float><<<dim3(5, 5, G), 256, 0, stream>>>(
            Q, (long long)Nn_ * Cc, Cc, Nn_, Kb, (long long)Nn_ * Cc, Cc, Nn_, nullptr,
            Sf, (long long)Nn_ * Np, Np, Cc, SCALE, nullptr, nullptr, nullptr);

        softmax_bf16<<<MR, 256, 0, stream>>>(Sf, Sb, tok + (long long)b0 * 576);

        // Yt[c, n] = sum_m Vt[c, m] * Sb[n, m]  (M=768, N=577 valid, K=640)
        mm_bf16<EPS_STORE, ushort_t><<<dim3(5, 6, G), 256, 0, stream>>>(
            Vt, (long long)Cc * Np, Np, Cc, Sb, (long long)Nn_ * Np, Np, Nn_, nullptr,
            Yt, (long long)Cc * Nn_, Nn_, Np, 1.f, nullptr, nullptr, nullptr);

        // x2 = 2*(Yt_flat @ proj_w^T + proj_b) -> d_out rows of group (fp32)
        mm_bf16<EPS_X2, float><<<dim3(6, myM, 1), 256, 0, stream>>>(
            Yt, 0, Cc, MR, wp, 0, Cc, Cc, proj_b,
            x2 + (long long)b0 * Nn_ * Cc, 0, Cc, Cc, 1.f, nullptr, nullptr, nullptr);
    }

    // ================= phase B: MLP per chunk of CH rows =================
    for (int c0 = 0; c0 < Mrows; c0 += CH) {
        const int myC = (CH + 127) / 128;

        ln_bf16<<<CH, 256, 0, stream>>>(x2 + (long long)c0 * Cc, n2w, n2b, g);

        // t = gelu(g @ fc1^T + b1)  (CH x 3072 x 768), bf16
        mm_bf16<EPS_GELU, ushort_t><<<dim3(24, myC, 1), 256, 0, stream>>>(
            g, 0, Cc, CH, w1, 0, Cc, Hh, fc1b,
            t, 0, Hh, Cc, 1.f, nullptr, nullptr, nullptr);

        // x2 += t @ fc2^T + b2      (CH x 768 x 3072), fp32 accumulate
        mm_bf16<EPS_ACC, float><<<dim3(6, myC, 1), 256, 0, stream>>>(
            t, 0, Hh, CH, w2, 0, Hh, Cc, fc2b,
            x2 + (long long)c0 * Cc, 0, Cc, Hh, 1.f, nullptr, nullptr, nullptr);
    }
}

// Round 4
// 921.799 us; speedup vs baseline: 8.1668x; 1.0956x over previous
//
#include <hip/hip_runtime.h>
#include <hip/hip_bf16.h>

// ---------------- problem constants ----------------
#define Bz   32
#define Nn_  577
#define Np   640                    // 577 padded to 5*128
#define Cc   768
#define Hh   3072
#define Mrows (Bz * Nn_)            // 18464
#define OUT_X (Mrows * Cc)          // 14,180,352 floats
#define SCALE 0.03608439182435161f  // 768^-0.5

typedef unsigned short ushort_t;
typedef short short8 __attribute__((ext_vector_type(8)));
typedef float f32x4 __attribute__((ext_vector_type(4)));

__device__ __forceinline__ ushort_t f2b(float f) {
    __hip_bfloat16 h = __float2bfloat16(f);
    return *reinterpret_cast<ushort_t*>(&h);
}

// ---------------- async global->LDS (16B per lane) ----------------
__device__ __forceinline__ void gl16(const ushort_t* g, ushort_t* l) {
    __builtin_amdgcn_global_load_lds(
        (const __attribute__((address_space(1))) void*)g,
        (__attribute__((address_space(3))) void*)l, 16, 0, 0);
}

// ---------------- block reduction helpers (256-thread blocks) ----------------
__device__ __forceinline__ float bsum(float v, float* sm) {
    #pragma unroll
    for (int o = 32; o > 0; o >>= 1) v += __shfl_down(v, o, 64);
    int lane = threadIdx.x & 63, wid = threadIdx.x >> 6;
    if (lane == 0) sm[wid] = v;
    __syncthreads();
    float r = sm[0] + sm[1] + sm[2] + sm[3];
    __syncthreads();
    return r;
}
__device__ __forceinline__ float bmax(float v, float* sm) {
    #pragma unroll
    for (int o = 32; o > 0; o >>= 1) v = fmaxf(v, __shfl_down(v, o, 64));
    int lane = threadIdx.x & 63, wid = threadIdx.x >> 6;
    if (lane == 0) sm[wid] = v;
    __syncthreads();
    float r = fmaxf(fmaxf(sm[0], sm[1]), fmaxf(sm[2], sm[3]));
    __syncthreads();
    return r;
}

// ---------------- fp32 -> bf16 convert ----------------
__global__ void cvt_kernel(const float* __restrict__ in, ushort_t* __restrict__ out, int n) {
    int i = blockIdx.x * 256 + threadIdx.x;
    if (i < n) out[i] = f2b(in[i]);
}

// ---------------- LayerNorm: fp32 in, bf16 out ----------------
__global__ void ln_bf16(const float* __restrict__ x, const float* __restrict__ w,
                        const float* __restrict__ b, ushort_t* __restrict__ out) {
    __shared__ float sm[8];
    long long row = blockIdx.x;
    const float* xr = x + row * Cc;
    float v[3]; float s = 0.f;
    #pragma unroll
    for (int i = 0; i < 3; ++i) { v[i] = xr[threadIdx.x + i * 256]; s += v[i]; }
    float mu = bsum(s, sm) * (1.f / (float)Cc);
    float sq = 0.f;
    #pragma unroll
    for (int i = 0; i < 3; ++i) { float d = v[i] - mu; sq += d * d; }
    float var = bsum(sq, sm + 4) * (1.f / (float)Cc);
    float inv = rsqrtf(var + 1e-5f);
    ushort_t* orow = out + row * Cc;
    #pragma unroll
    for (int i = 0; i < 3; ++i) {
        int c = threadIdx.x + i * 256;
        orow[c] = f2b((v[i] - mu) * inv * w[c] + b[c]);
    }
}

// ---------------- softmax: fp32 Sf (ld 640, 577 valid) -> bf16 Sb (zero-padded) + tok ----------------
__global__ void softmax_bf16(const float* __restrict__ Sf, ushort_t* __restrict__ Sb,
                             float* __restrict__ tok) {
    __shared__ float sm[8];
    long long row = blockIdx.x;
    int b_l = (int)(row / Nn_), r = (int)(row - (long long)b_l * Nn_);
    const float* src = Sf + row * Np;
    ushort_t* dst = Sb + row * Np;
    float v[3]; float mx = -1e30f;
    #pragma unroll
    for (int i = 0; i < 3; ++i) {
        int c = threadIdx.x + i * 256;
        v[i] = (c < Nn_) ? src[c] : -1e30f;
        mx = fmaxf(mx, v[i]);
    }
    mx = bmax(mx, sm);
    float s = 0.f;
    #pragma unroll
    for (int i = 0; i < 3; ++i) {
        int c = threadIdx.x + i * 256;
        v[i] = (c < Nn_) ? expf(v[i] - mx) : 0.f;
        s += v[i];
    }
    s = bsum(s, sm + 4);
    float inv = 1.f / s;
    #pragma unroll
    for (int i = 0; i < 3; ++i) {
        int c = threadIdx.x + i * 256;
        float p = v[i] * inv;
        if (c < Np) dst[c] = (c < Nn_) ? f2b(p) : (ushort_t)0;
        if (r == 0 && c >= 1 && c < Nn_) tok[(long long)b_l * 576 + (c - 1)] = p;
    }
}

// ---------------- bf16 MFMA GEMM: C[m,n] = alpha*sum_k A[m,k]*B[n,k] (+epilogue) ----------------
// A: M x K rows (lda), row-clamped. B: Nv x K rows (ldb), row-clamped.
// z-dim: batch index (strides sAb/sBb/sOb). For split-K, z = split and
// sAb/sBb = k-offset (elements), sOb = 0, EPI = EPS_ATOMIC (bias only when z==0).
// LDS uses XOR-swizzled 16B quarters: slot q' holds global quarter q'^(row&3),
// applied on the global-source side (global_load_lds lane->LDS map is fixed).
#define EPS_STORE  0
#define EPS_X2     1
#define EPS_GELU   2
#define EPS_ATOMIC 3
#define EPS_QKV    4

template<int EPI, typename OutT>
__global__ __launch_bounds__(256)
void mm_bf16(const ushort_t* __restrict__ A, long long sAb, int lda, int M,
             const ushort_t* __restrict__ B, long long sBb, int ldb, int Nv,
             const float* __restrict__ bias,
             OutT* __restrict__ O, long long sOb, int ldo,
             int K, float alpha,
             ushort_t* __restrict__ qQ, ushort_t* __restrict__ qK, ushort_t* __restrict__ qV)
{
    __shared__ __align__(16) ushort_t As[128 * 32];
    __shared__ __align__(16) ushort_t Bs[128 * 32];
    const int z = blockIdx.z;
    A += (long long)z * sAb; B += (long long)z * sBb;
    if (O) O += (long long)z * sOb;
    const int n0 = blockIdx.x * 128;
    const int m0 = blockIdx.y * 128;
    const int tid = threadIdx.x;
    const int lane = tid & 63;
    const int wv = tid >> 6;
    const int wr = (wv >> 1) << 6;       // wave row offset in tile
    const int wc = (wv & 1) << 6;        // wave col offset in tile
    const int fr = lane & 15;
    const int kq = lane >> 4;            // k-quarter 0..3

    // staging: LDS chunk element e (ushorts) -> row = e>>5, lds quarter q' = (e&31)>>3,
    // source global quarter q = q' ^ (row&3).
    const int e0 = tid * 8, e1 = 2048 + tid * 8;
    const int ra0 = e0 >> 5, qa0 = (((e0 & 31) >> 3) ^ (ra0 & 3)) << 3;
    const int ra1 = e1 >> 5, qa1 = (((e1 & 31) >> 3) ^ (ra1 & 3)) << 3;
    const ushort_t* Ag0 = A + (long long)min(m0 + ra0, M - 1) * lda + qa0;
    const ushort_t* Ag1 = A + (long long)min(m0 + ra1, M - 1) * lda + qa1;
    const ushort_t* Bg0 = B + (long long)min(n0 + ra0, Nv - 1) * ldb + qa0;
    const ushort_t* Bg1 = B + (long long)min(n0 + ra1, Nv - 1) * ldb + qa1;

    f32x4 acc[4][4] = {};

    for (int k0 = 0; k0 < K; k0 += 32) {
        gl16(Ag0 + k0, &As[e0]);
        gl16(Ag1 + k0, &As[e1]);
        gl16(Bg0 + k0, &Bs[e0]);
        gl16(Bg1 + k0, &Bs[e1]);
        __syncthreads();
        short8 af[4], bfr[4];
        #pragma unroll
        for (int i = 0; i < 4; ++i) {
            int r = wr + i * 16 + fr;
            af[i] = *(const short8*)&As[r * 32 + ((kq ^ (r & 3)) << 3)];
        }
        #pragma unroll
        for (int j = 0; j < 4; ++j) {
            int r = wc + j * 16 + fr;
            bfr[j] = *(const short8*)&Bs[r * 32 + ((kq ^ (r & 3)) << 3)];
        }
        #pragma unroll
        for (int i = 0; i < 4; ++i)
            #pragma unroll
            for (int j = 0; j < 4; ++j)
                acc[i][j] = __builtin_amdgcn_mfma_f32_16x16x32_bf16(af[i], bfr[j], acc[i][j], 0, 0, 0);
        __syncthreads();
    }

    // epilogue: C row m = m0+wr+i*16+(lane>>4)*4+r ; col n = n0+wc+j*16+(lane&15)
    #pragma unroll
    for (int i = 0; i < 4; ++i) {
        int mb = m0 + wr + i * 16 + (lane >> 4) * 4;
        #pragma unroll
        for (int j = 0; j < 4; ++j) {
            int n = n0 + wc + j * 16 + fr;
            if (n >= Nv) continue;
            f32x4 v4 = acc[i][j];
            #pragma unroll
            for (int r = 0; r < 4; ++r) {
                int m = mb + r;
                if (m >= M) continue;
                float v = v4[r] * alpha;
                if constexpr (EPI == EPS_QKV) {
                    int b_l = m / Nn_, rr = m - b_l * Nn_;
                    if (n < Cc)            qQ[(long long)m * Cc + n] = f2b(v);
                    else if (n < 2 * Cc)   qK[(long long)m * Cc + (n - Cc)] = f2b(v);
                    else                   qV[((long long)b_l * Cc + (n - 2 * Cc)) * Np + rr] = f2b(v);
                } else if constexpr (EPI == EPS_ATOMIC) {
                    if (bias && z == 0) v += bias[n];
                    atomicAdd(&O[(long long)m * ldo + n], v);
                } else {
                    if (bias) v += bias[n];
                    if constexpr (EPI == EPS_X2) v *= 2.f;
                    if constexpr (EPI == EPS_GELU) v = 0.5f * v * (1.f + erff(v * 0.70710678118654752f));
                    long long oi = (long long)m * ldo + n;
                    if constexpr (sizeof(OutT) == 2) O[oi] = (OutT)f2b(v);
                    else                             O[oi] = (OutT)v;
                }
            }
        }
    }
}

// ---------------- launcher ----------------
extern "C" void kernel_launch(void* const* d_in, const int* in_sizes, int n_in,
                              void* d_out, int out_size, void* d_ws, size_t ws_size,
                              hipStream_t stream) {
    const float* x      = (const float*)d_in[0];
    const float* n1w    = (const float*)d_in[1];
    const float* n1b    = (const float*)d_in[2];
    const float* qkv_w  = (const float*)d_in[3];
    const float* proj_w = (const float*)d_in[4];
    const float* proj_b = (const float*)d_in[5];
    const float* n2w    = (const float*)d_in[6];
    const float* n2b    = (const float*)d_in[7];
    const float* fc1w   = (const float*)d_in[8];
    const float* fc1b   = (const float*)d_in[9];
    const float* fc2w   = (const float*)d_in[10];
    const float* fc2b   = (const float*)d_in[11];
    float* out = (float*)d_out;
    float* x2  = out;
    float* tok = out + OUT_X;

    // ---- persistent bf16 weights at ws start ----
    char* ws = (char*)d_ws;
    const long long nWq = (long long)3 * Cc * Cc;
    const long long nWp = (long long)Cc * Cc;
    const long long nW1 = (long long)Hh * Cc;
    const long long nW2 = (long long)Cc * Hh;
    ushort_t* wq = (ushort_t*)ws;
    ushort_t* wp = wq + nWq;
    ushort_t* w1 = wp + nWp;
    ushort_t* w2 = w1 + nW1;
    const long long WBYTES = 2 * (nWq + nWp + nW1 + nW2); // 14,155,776
    char* dyn = ws + WBYTES;
    long long avail = (long long)ws_size - WBYTES;

    // ---- adaptive sizes (prefer no chunking: G=32, CH=full) ----
    const long long perG = 3LL * Nn_ * Cc * 2 + (long long)Cc * Np * 2
                         + (long long)Nn_ * Np * 4 + (long long)Nn_ * Np * 2;
    int G = 1;
    { const int o[6] = {32, 16, 8, 4, 2, 1};
      for (int i = 0; i < 6; ++i) if ((long long)o[i] * perG <= avail) { G = o[i]; break; } }
    int CH = Nn_;
    { const int o[6] = {32, 16, 8, 4, 2, 1};
      for (int i = 0; i < 6; ++i) if ((long long)o[i] * Nn_ * (Cc + Hh) * 2 <= avail) { CH = o[i] * Nn_; break; } }

    // phase A layout: hbf/Yt | Q | Kb | Vt | Sf | Sb
    ushort_t* hbf = (ushort_t*)dyn;
    ushort_t* Q   = hbf + (long long)G * Nn_ * Cc;
    ushort_t* Kb  = Q   + (long long)G * Nn_ * Cc;
    ushort_t* Vt  = Kb  + (long long)G * Nn_ * Cc;
    float*    Sf  = (float*)(Vt + (long long)G * Cc * Np);
    ushort_t* Sb  = (ushort_t*)(Sf + (long long)G * Nn_ * Np);
    ushort_t* Yt  = hbf;
    // phase B layout: g | t
    ushort_t* g = (ushort_t*)dyn;
    ushort_t* t = g + (long long)CH * Cc;

    // ---- weight conversion (every call; ws is re-poisoned) ----
    cvt_kernel<<<(int)((nWq + 255) / 256), 256, 0, stream>>>(qkv_w, wq, (int)nWq);
    cvt_kernel<<<(int)((nWp + 255) / 256), 256, 0, stream>>>(proj_w, wp, (int)nWp);
    cvt_kernel<<<(int)((nW1 + 255) / 256), 256, 0, stream>>>(fc1w, w1, (int)nW1);
    cvt_kernel<<<(int)((nW2 + 255) / 256), 256, 0, stream>>>(fc2w, w2, (int)nW2);

    // ================= phase A: attention per group of G batches =================
    for (int b0 = 0; b0 < Bz; b0 += G) {
        const int MR = G * Nn_;
        const int myM = (MR + 127) / 128;

        ln_bf16<<<MR, 256, 0, stream>>>(x + (long long)b0 * Nn_ * Cc, n1w, n1b, hbf);

        // qkv: (MR x 2304 x 768), scatter to Q | Kb | Vt
        mm_bf16<EPS_QKV, float><<<dim3(18, myM, 1), 256, 0, stream>>>(
            hbf, 0, Cc, MR, wq, 0, Cc, 3 * Cc, nullptr,
            (float*)nullptr, 0, 0, Cc, 1.f, Q, Kb, Vt);

        // Sf = scale * Q @ K^T per batch (577x577 valid, ld 640)
        mm_bf16<EPS_STORE, float><<<dim3(5, 5, G), 256, 0, stream>>>(
            Q, (long long)Nn_ * Cc, Cc, Nn_, Kb, (long long)Nn_ * Cc, Cc, Nn_, nullptr,
            Sf, (long long)Nn_ * Np, Np, Cc, SCALE, nullptr, nullptr, nullptr);

        softmax_bf16<<<MR, 256, 0, stream>>>(Sf, Sb, tok + (long long)b0 * 576);

        // Yt[c, n] = sum_m Vt[c, m] * Sb[n, m]  (M=768, N=577 valid, K=640)
        mm_bf16<EPS_STORE, ushort_t><<<dim3(5, 6, G), 256, 0, stream>>>(
            Vt, (long long)Cc * Np, Np, Cc, Sb, (long long)Nn_ * Np, Np, Nn_, nullptr,
            Yt, (long long)Cc * Nn_, Nn_, Np, 1.f, nullptr, nullptr, nullptr);

        // x2 = 2*(Yt_flat @ proj_w^T + proj_b) -> d_out rows of group (fp32)
        mm_bf16<EPS_X2, float><<<dim3(6, myM, 1), 256, 0, stream>>>(
            Yt, 0, Cc, MR, wp, 0, Cc, Cc, proj_b,
            x2 + (long long)b0 * Nn_ * Cc, 0, Cc, Cc, 1.f, nullptr, nullptr, nullptr);
    }

    // ================= phase B: MLP per chunk of CH rows =================
    for (int c0 = 0; c0 < Mrows; c0 += CH) {
        const int cn = (Mrows - c0 < CH) ? (Mrows - c0) : CH;
        const int myC = (cn + 127) / 128;

        ln_bf16<<<cn, 256, 0, stream>>>(x2 + (long long)c0 * Cc, n2w, n2b, g);

        // t = gelu(g @ fc1^T + b1)  (cn x 3072 x 768), bf16
        mm_bf16<EPS_GELU, ushort_t><<<dim3(24, myC, 1), 256, 0, stream>>>(
            g, 0, Cc, cn, w1, 0, Cc, Hh, fc1b,
            t, 0, Hh, Cc, 1.f, nullptr, nullptr, nullptr);

        // x2 += t @ fc2^T + b2  (cn x 768 x 3072), split-K=2, fp32 atomic accumulate
        mm_bf16<EPS_ATOMIC, float><<<dim3(6, myC, 2), 256, 0, stream>>>(
            t, Hh / 2, Hh, cn, w2, Hh / 2, Hh, Cc, fc2b,
            x2 + (long long)c0 * Cc, 0, Cc, Hh / 2, 1.f, nullptr, nullptr, nullptr);
    }
}